// Round 19
// baseline (228.937 us; speedup 1.0000x reference)
//
#include <hip/hip_runtime.h>
#include <hip/hip_bf16.h>

// CoreAttention (ChatGLM GQA fallback) — swapped-operand 32x32x16 bf16 MFMA
// flash attention. Round 19: THREE-WAY STREAM BODY. pf carried across the
// barrier so body(t) = { PV(t-1) | softmax(t) | QK(t+1) } — three mutually
// independent streams in one fence-free region (compiler interleaves MFMA
// issue into the softmax VALU chain from a single wave). V buffers 4-deep;
// K/M 2-deep; prologue zeroes Vt[3]+pfA so PV(-1) is an exact no-op; final
// PV(NT-1) after the loop. Head-octet blocks (8 waves = 8 heads sharing
// K/V/mask LDS staged via global_load_lds from pre-swizzled bf16 images).
// B=2, H=32, G=2, Q=KV=2048, D=128, fp32 in/out.

constexpr int Bn = 2, Hn = 32, Gn = 2, Qn = 2048, KVn = 2048, Dn = 128;
constexpr int WAVES = 8, QBLK = 32, HO = 8;           // 8 heads/block
constexpr int KVB = 64, NT = KVn / KVB;               // 32 kv tiles of 64
constexpr int NT32 = KVn / 32;
constexpr float SCALE = 0.08838834764831843f;         // 1/sqrt(128)
constexpr float L2E = 1.4426950408889634f;
constexpr float SCALE2 = SCALE * L2E;

constexpr size_t WSK_BYTES = (size_t)Bn * Gn * KVn * 256;   // 2 MiB

typedef __attribute__((ext_vector_type(16))) float f32x16;
typedef __attribute__((ext_vector_type(8))) __bf16 bf16x8;
typedef __attribute__((ext_vector_type(2))) unsigned u32x2;

union Frag { unsigned u[4]; bf16x8 b; };

__device__ __forceinline__ unsigned pk2(float a, float b) {
  union { __bf16 h[2]; unsigned u; } x;
  x.h[0] = (__bf16)a; x.h[1] = (__bf16)b;
  return x.u;
}

__global__ __launch_bounds__(256)
void prepack(const float* __restrict__ Kg, const float* __restrict__ Vg,
             char* __restrict__ wsK, char* __restrict__ wsV) {
  const int i = blockIdx.x * 256 + threadIdx.x;   // [0, 524288)
  {  // K pair: dp = d/2
    const int dp = i & 63, kv = (i >> 6) & (KVn - 1), bg = i >> 17;
    const float* src = Kg + ((size_t)bg * KVn + kv) * Dn + 2 * dp;
    const unsigned pr = pk2(src[0], src[1]);
    const size_t off = (size_t)bg * (KVn * 256) + (size_t)kv * 256
                       + ((4 * dp) ^ ((kv & 15) << 4));
    *(unsigned*)(wsK + off) = pr;
  }
  {  // V^T pair: (kv=2vkp, 2vkp+1) at row d, 32-kv subtile t
    const int d = i & 127, vg = (i >> 7) & 1023, bg = i >> 17;
    const int t = vg >> 4, vkp = vg & 15;
    const float* src = Vg + ((size_t)bg * KVn + t * 32 + 2 * vkp) * Dn + d;
    const unsigned pr = pk2(src[0], src[Dn]);
    const int slot = (((d >> 3) ^ (d >> 1)) & 3) << 4;
    const size_t off = ((size_t)bg * NT32 + t) * 8192 + (d << 6)
                       + ((vkp * 4) ^ slot);
    *(unsigned*)(wsV + off) = pr;
  }
}

__global__ __launch_bounds__(512, 2)
void attn_fwd(const float* __restrict__ Qg, const float* __restrict__ Mg,
              const char* __restrict__ wsK, const char* __restrict__ wsV,
              float* __restrict__ Og) {
  __shared__ __align__(16) short Ks[2][KVB * Dn];    // 16KB x2
  __shared__ __align__(16) short Vt[4][Dn * KVB];    // 16KB x4 (4-deep)
  __shared__ __align__(16) float Ms[2][QBLK * KVB];  // 8KB x2 (swizzled rows)

  const int tid = threadIdx.x;
  const int lane = tid & 63, w = tid >> 6;           // w in [0,8)
  const int hi = lane >> 5, ln = lane & 31;
  const int qb = blockIdx.x * QBLK, ho = blockIdx.y, b = blockIdx.z;
  const int h = ho * HO + w;                         // wave's head
  const int g = ho >> 1, bg = b * Gn + g;            // octet shares g

  // ---- Q B-fragments, PRE-SCALED: aq[ks][j] = Q[h][qb+ln][ks*16+hi*8+j]*SCALE2
  bf16x8 aq[8];
  {
    const float* qr = Qg + ((size_t)(b * Hn + h) * Qn + qb + ln) * Dn + hi * 8;
#pragma unroll
    for (int ks = 0; ks < 8; ++ks) {
      float4 f0 = *(const float4*)(qr + ks * 16);
      float4 f1 = *(const float4*)(qr + ks * 16 + 4);
      union { unsigned u[4]; bf16x8 b; } t;
      t.u[0] = pk2(f0.x * SCALE2, f0.y * SCALE2);
      t.u[1] = pk2(f0.z * SCALE2, f0.w * SCALE2);
      t.u[2] = pk2(f1.x * SCALE2, f1.y * SCALE2);
      t.u[3] = pk2(f1.z * SCALE2, f1.w * SCALE2);
      aq[ks] = t.b;
    }
  }

  // ---- incremental staging pointers ----
  const char* wsKb = wsK + (size_t)bg * (KVn * 256);
  const char* wsVb = wsV + (size_t)bg * (KVn * 256);
  const int mr = w * 4 + (lane >> 4);
  const int mc = (lane & 15) << 4;
  const char* pK = wsKb + w * 2048 + lane * 16;
  const char* pV = wsVb + w * 2048 + lane * 16;
  const char* pM = (const char*)Mg + (size_t)(b * Qn + qb + mr) * (KVn * 4)
                   + (mc ^ ((mr & 15) << 4));
  char* dK0 = (char*)Ks[0] + w * 2048; char* dK1 = (char*)Ks[1] + w * 2048;
  char* const vtBase = (char*)Vt[0];
  char* const dVw = vtBase + w * 2048;               // + slot*16384
  char* dM0 = (char*)Ms[0] + w * 1024; char* dM1 = (char*)Ms[1] + w * 1024;

  auto gll = [](const char* s, char* d) {
    __builtin_amdgcn_global_load_lds(
        (const __attribute__((address_space(1))) void*)s,
        (__attribute__((address_space(3))) void*)d, 16, 0, 0);
  };
  auto stageK = [&](char* dk) { gll(pK, dk); gll(pK + 1024, dk + 1024); };

  const int ksw = (ln & 15) << 4;
  const int msw = (ln & 15) << 4;
  const char* msb0 = (const char*)Ms[0] + ln * 256;
  const char* msb1 = (const char*)Ms[1] + ln * 256;

  auto qk = [&](const char* ksb, f32x16& t0, f32x16& t1) {
#pragma unroll
    for (int e = 0; e < 16; ++e) { t0[e] = 0.0f; t1[e] = 0.0f; }
#pragma unroll
    for (int ks = 0; ks < 8; ++ks) {
      const int byte = (ks * 32 + hi * 16) ^ ksw;
      bf16x8 k0 = *(const bf16x8*)(ksb + (ln << 8) + byte);
      bf16x8 k1 = *(const bf16x8*)(ksb + ((32 + ln) << 8) + byte);
      t0 = __builtin_amdgcn_mfma_f32_32x32x16_bf16(k0, aq[ks], t0, 0, 0, 0);
      t1 = __builtin_amdgcn_mfma_f32_32x32x16_bf16(k1, aq[ks], t1, 0, 0, 0);
    }
  };

  f32x16 o[4];
#pragma unroll
  for (int nt = 0; nt < 4; ++nt)
#pragma unroll
    for (int e = 0; e < 16; ++e) o[nt][e] = 0.0f;
  float lsum = 0.0f;

  // body(t): stage K(t+2)/V(t+1)/M(t+1); then three independent streams:
  //   PV(t-1) [pfPrev + Vt[(t-1)&3]],  softmax(t) [sC + Ms[t&1]],
  //   QK(t+1) [Ks[(t+1)&1] -> sN];  pfCur from own;  one barrier.
  auto body = [&](int t, f32x16& sC0, f32x16& sC1, f32x16& sN0, f32x16& sN1,
                  Frag (&pfPrev)[4], Frag (&pfCur)[4]) {
    const int cur = t & 1;

    stageK(cur ? dK1 : dK0);                         // K(t+2) -> slot t&1
    {
      char* dv = dVw + ((t + 1) & 3) * 16384;        // V(t+1) -> slot (t+1)&3
      gll(pV, dv); gll(pV + 1024, dv + 1024);
      gll(pM, cur ? dM0 : dM1);                      // M(t+1) -> slot (t+1)&1
    }
    if (t + 3 < NT) pK += 16384;
    if (t + 2 < NT) { pV += 16384; pM += 256; }
    __builtin_amdgcn_sched_barrier(0);

    // ---- stream 1: softmax(t) ----
    const char* msb = cur ? msb1 : msb0;
    unsigned own0[8], own1[8];
    float psum = 0.0f;
#pragma unroll
    for (int gq = 0; gq < 4; ++gq) {
      float4 m0 = *(const float4*)(msb + ((gq * 32 + hi * 16) ^ msw));
      float4 m1 = *(const float4*)(msb + ((128 + gq * 32 + hi * 16) ^ msw));
      float p0 = __builtin_exp2f(__builtin_fmaf(m0.x, L2E, sC0[4 * gq + 0]));
      float p1 = __builtin_exp2f(__builtin_fmaf(m0.y, L2E, sC0[4 * gq + 1]));
      float p2 = __builtin_exp2f(__builtin_fmaf(m0.z, L2E, sC0[4 * gq + 2]));
      float p3 = __builtin_exp2f(__builtin_fmaf(m0.w, L2E, sC0[4 * gq + 3]));
      float q0 = __builtin_exp2f(__builtin_fmaf(m1.x, L2E, sC1[4 * gq + 0]));
      float q1 = __builtin_exp2f(__builtin_fmaf(m1.y, L2E, sC1[4 * gq + 1]));
      float q2 = __builtin_exp2f(__builtin_fmaf(m1.z, L2E, sC1[4 * gq + 2]));
      float q3 = __builtin_exp2f(__builtin_fmaf(m1.w, L2E, sC1[4 * gq + 3]));
      psum += ((p0 + p1) + (p2 + p3)) + ((q0 + q1) + (q2 + q3));
      own0[2 * gq] = pk2(p0, p1); own0[2 * gq + 1] = pk2(p2, p3);
      own1[2 * gq] = pk2(q0, q1); own1[2 * gq + 1] = pk2(q2, q3);
    }
    lsum += psum;

    // ---- stream 2: QK(t+1) -> sN (independent of sC/pfPrev) ----
    qk((const char*)Ks[cur ^ 1], sN0, sN1);

    // ---- stream 3: PV(t-1): o += V(t-1) x pfPrev ----
    {
      const char* vtb = vtBase + ((t + 3) & 3) * 16384;
#pragma unroll
      for (int nt = 0; nt < 4; ++nt) {
        const int d = nt * 32 + ln;
        const int swz = (((d >> 3) ^ (d >> 1)) & 3) << 4;
#pragma unroll
        for (int ks = 0; ks < 4; ++ks) {
          const int base = (ks >> 1) * 8192 + (d << 6);
          bf16x8 vfr = *(const bf16x8*)(vtb + base + (((ks & 1) * 32 + hi * 16) ^ swz));
          o[nt] = __builtin_amdgcn_mfma_f32_32x32x16_bf16(vfr, pfPrev[ks].b, o[nt], 0, 0, 0);
        }
      }
    }

    // ---- pfCur from own (permlane32_swap; verified) ----
#pragma unroll
    for (int ks = 0; ks < 4; ++ks) {
      const unsigned* ow = (ks < 2) ? own0 : own1;
      const int bsl = (ks & 1) * 4;
#if __has_builtin(__builtin_amdgcn_permlane32_swap)
      u32x2 r0 = __builtin_amdgcn_permlane32_swap(ow[bsl + 0], ow[bsl + 2], false, false);
      u32x2 r1 = __builtin_amdgcn_permlane32_swap(ow[bsl + 1], ow[bsl + 3], false, false);
      pfCur[ks].u[0] = r0.x; pfCur[ks].u[2] = r0.y;
      pfCur[ks].u[1] = r1.x; pfCur[ks].u[3] = r1.y;
#else
      unsigned sA = __shfl_xor(ow[bsl + 0], 32), sCx = __shfl_xor(ow[bsl + 2], 32);
      unsigned sB = __shfl_xor(ow[bsl + 1], 32), sD = __shfl_xor(ow[bsl + 3], 32);
      pfCur[ks].u[0] = hi ? sCx : ow[bsl + 0];
      pfCur[ks].u[1] = hi ? sD : ow[bsl + 1];
      pfCur[ks].u[2] = hi ? ow[bsl + 2] : sA;
      pfCur[ks].u[3] = hi ? ow[bsl + 3] : sB;
#endif
    }

    __syncthreads();
  };

  // ---- prologue: K(0),K(1); V/M(0); zero Vt[3]; QK(0)->sA; pfA=0 ----
  stageK(dK0); pK += 16384;
  stageK(dK1); pK += 16384;
  {
    gll(pV, dVw); gll(pV + 1024, dVw + 1024);        // V(0) -> slot 0
    gll(pM, dM0);                                    // M(0) -> slot 0
    pV += 16384; pM += 256;
  }
  {  // zero Vt[3] so body(0)'s PV(-1) reads exact 0.0 (no NaN risk)
    char* z = vtBase + 3 * 16384 + tid * 32;
    *(uint4*)z = make_uint4(0, 0, 0, 0);
    *(uint4*)(z + 16) = make_uint4(0, 0, 0, 0);
  }
  __syncthreads();
  f32x16 sA0, sA1, sB0, sB1;
  qk((const char*)Ks[0], sA0, sA1);
  __syncthreads();   // all waves done reading Ks[0] before body(0) restages it

  Frag pfA[4], pfB[4];
#pragma unroll
  for (int i = 0; i < 4; ++i) {
    pfA[i].u[0] = 0; pfA[i].u[1] = 0; pfA[i].u[2] = 0; pfA[i].u[3] = 0;
  }

  for (int t = 0; t < NT; t += 2) {
    body(t,     sA0, sA1, sB0, sB1, pfA, pfB);
    body(t + 1, sB0, sB1, sA0, sA1, pfB, pfA);
  }

  // ---- final PV(NT-1): o += V(NT-1) x pfA ----
  {
    const char* vtb = vtBase + ((NT - 1) & 3) * 16384;
#pragma unroll
    for (int nt = 0; nt < 4; ++nt) {
      const int d = nt * 32 + ln;
      const int swz = (((d >> 3) ^ (d >> 1)) & 3) << 4;
#pragma unroll
      for (int ks = 0; ks < 4; ++ks) {
        const int base = (ks >> 1) * 8192 + (d << 6);
        bf16x8 vfr = *(const bf16x8*)(vtb + base + (((ks & 1) * 32 + hi * 16) ^ swz));
        o[nt] = __builtin_amdgcn_mfma_f32_32x32x16_bf16(vfr, pfA[ks].b, o[nt], 0, 0, 0);
      }
    }
  }

  // ---- epilogue: O^T/l, write context[q][b][h*128+d] ----
  const float ltot = lsum + __shfl_xor(lsum, 32);
  const float invl = 1.0f / ltot;
  float* outp = Og + (size_t)(qb + ln) * (Bn * Hn * Dn) + (size_t)b * (Hn * Dn) + h * Dn;
#pragma unroll
  for (int nt = 0; nt < 4; ++nt)
#pragma unroll
    for (int gq = 0; gq < 4; ++gq) {
      float4 v;
      v.x = o[nt][gq * 4 + 0] * invl;
      v.y = o[nt][gq * 4 + 1] * invl;
      v.z = o[nt][gq * 4 + 2] * invl;
      v.w = o[nt][gq * 4 + 3] * invl;
      *(float4*)(outp + nt * 32 + gq * 8 + hi * 4) = v;
    }
}

extern "C" void kernel_launch(void* const* d_in, const int* in_sizes, int n_in,
                              void* d_out, int out_size, void* d_ws, size_t ws_size,
                              hipStream_t stream) {
  const float* q = (const float*)d_in[0];
  const float* k = (const float*)d_in[1];
  const float* v = (const float*)d_in[2];
  const float* m = (const float*)d_in[3];
  float* out = (float*)d_out;
  char* wsK = (char*)d_ws;
  char* wsV = wsK + WSK_BYTES;

  prepack<<<dim3((Bn * Gn * KVn * 64) / 256), 256, 0, stream>>>(k, v, wsK, wsV);
  dim3 grid(Qn / QBLK, Hn / HO, Bn);
  attn_fwd<<<grid, WAVES * 64, 0, stream>>>(q, m, wsK, wsV, out);
}

// Round 20
// 220.130 us; speedup vs baseline: 1.0400x; 1.0400x over previous
//
#include <hip/hip_runtime.h>
#include <hip/hip_bf16.h>

// CoreAttention (ChatGLM GQA fallback) — swapped-operand 32x32x16 bf16 MFMA
// flash attention. Round 20: REVERT to r18 (best, 214.8 us). r19's deferred-
// PV three-stream body regressed (compiler already overlapped QK(t+1) with
// softmax in r18; deferral only added VGPR+LDS+live-range cost).
// r18 = 2-stage pipeline (QK(t+1) computed alongside softmax+PV(t)) +
// incremental staging pointers + softmax-first body ordering. Head-octet
// blocks: 8 waves = 8 heads sharing K/V/mask LDS tiles staged via
// global_load_lds from pre-swizzled bf16 images (prepack kernel, d_ws).
// B=2, H=32, G=2, Q=KV=2048, D=128, fp32 in/out.

constexpr int Bn = 2, Hn = 32, Gn = 2, Qn = 2048, KVn = 2048, Dn = 128;
constexpr int WAVES = 8, QBLK = 32, HO = 8;           // 8 heads/block
constexpr int KVB = 64, NT = KVn / KVB;               // 32 kv tiles of 64
constexpr int NT32 = KVn / 32;
constexpr float SCALE = 0.08838834764831843f;         // 1/sqrt(128)
constexpr float L2E = 1.4426950408889634f;
constexpr float SCALE2 = SCALE * L2E;

constexpr size_t WSK_BYTES = (size_t)Bn * Gn * KVn * 256;   // 2 MiB

typedef __attribute__((ext_vector_type(16))) float f32x16;
typedef __attribute__((ext_vector_type(8))) __bf16 bf16x8;
typedef __attribute__((ext_vector_type(2))) unsigned u32x2;

__device__ __forceinline__ unsigned pk2(float a, float b) {
  union { __bf16 h[2]; unsigned u; } x;
  x.h[0] = (__bf16)a; x.h[1] = (__bf16)b;
  return x.u;
}

__global__ __launch_bounds__(256)
void prepack(const float* __restrict__ Kg, const float* __restrict__ Vg,
             char* __restrict__ wsK, char* __restrict__ wsV) {
  const int i = blockIdx.x * 256 + threadIdx.x;   // [0, 524288)
  {  // K pair: dp = d/2
    const int dp = i & 63, kv = (i >> 6) & (KVn - 1), bg = i >> 17;
    const float* src = Kg + ((size_t)bg * KVn + kv) * Dn + 2 * dp;
    const unsigned pr = pk2(src[0], src[1]);
    const size_t off = (size_t)bg * (KVn * 256) + (size_t)kv * 256
                       + ((4 * dp) ^ ((kv & 15) << 4));
    *(unsigned*)(wsK + off) = pr;
  }
  {  // V^T pair: (kv=2vkp, 2vkp+1) at row d, 32-kv subtile t
    const int d = i & 127, vg = (i >> 7) & 1023, bg = i >> 17;
    const int t = vg >> 4, vkp = vg & 15;
    const float* src = Vg + ((size_t)bg * KVn + t * 32 + 2 * vkp) * Dn + d;
    const unsigned pr = pk2(src[0], src[Dn]);
    const int slot = (((d >> 3) ^ (d >> 1)) & 3) << 4;
    const size_t off = ((size_t)bg * NT32 + t) * 8192 + (d << 6)
                       + ((vkp * 4) ^ slot);
    *(unsigned*)(wsV + off) = pr;
  }
}

__global__ __launch_bounds__(512, 2)
void attn_fwd(const float* __restrict__ Qg, const float* __restrict__ Mg,
              const char* __restrict__ wsK, const char* __restrict__ wsV,
              float* __restrict__ Og) {
  __shared__ __align__(16) short Ks[2][KVB * Dn];    // 16KB x2
  __shared__ __align__(16) short Vt[2][Dn * KVB];    // 16KB x2
  __shared__ __align__(16) float Ms[2][QBLK * KVB];  // 8KB x2 (swizzled rows)

  const int tid = threadIdx.x;
  const int lane = tid & 63, w = tid >> 6;           // w in [0,8)
  const int hi = lane >> 5, ln = lane & 31;
  const int qb = blockIdx.x * QBLK, ho = blockIdx.y, b = blockIdx.z;
  const int h = ho * HO + w;                         // wave's head
  const int g = ho >> 1, bg = b * Gn + g;            // octet shares g

  // ---- Q B-fragments, PRE-SCALED: aq[ks][j] = Q[h][qb+ln][ks*16+hi*8+j]*SCALE2
  bf16x8 aq[8];
  {
    const float* qr = Qg + ((size_t)(b * Hn + h) * Qn + qb + ln) * Dn + hi * 8;
#pragma unroll
    for (int ks = 0; ks < 8; ++ks) {
      float4 f0 = *(const float4*)(qr + ks * 16);
      float4 f1 = *(const float4*)(qr + ks * 16 + 4);
      union { unsigned u[4]; bf16x8 b; } t;
      t.u[0] = pk2(f0.x * SCALE2, f0.y * SCALE2);
      t.u[1] = pk2(f0.z * SCALE2, f0.w * SCALE2);
      t.u[2] = pk2(f1.x * SCALE2, f1.y * SCALE2);
      t.u[3] = pk2(f1.z * SCALE2, f1.w * SCALE2);
      aq[ks] = t.b;
    }
  }

  // ---- incremental staging pointers (advance by constants; no per-tile mults)
  const char* wsKb = wsK + (size_t)bg * (KVn * 256);
  const char* wsVb = wsV + (size_t)bg * (KVn * 256);
  const int mr = w * 4 + (lane >> 4);
  const int mc = (lane & 15) << 4;
  const char* pM0 = (const char*)Mg + (size_t)(b * Qn + qb + mr) * (KVn * 4)
                    + (mc ^ ((mr & 15) << 4));
  const char* pK = wsKb + w * 2048 + lane * 16;      // K src, tile 0
  const char* pV = wsVb + w * 2048 + lane * 16;      // V src, tile 0
  const char* pM = pM0;                              // M src, tile 0
  char* dK0 = (char*)Ks[0] + w * 2048; char* dK1 = (char*)Ks[1] + w * 2048;
  char* dV0 = (char*)Vt[0] + w * 2048; char* dV1 = (char*)Vt[1] + w * 2048;
  char* dM0 = (char*)Ms[0] + w * 1024; char* dM1 = (char*)Ms[1] + w * 1024;

  auto gll = [](const char* s, char* d) {
    __builtin_amdgcn_global_load_lds(
        (const __attribute__((address_space(1))) void*)s,
        (__attribute__((address_space(3))) void*)d, 16, 0, 0);
  };
  auto stageK = [&](char* dk) { gll(pK, dk); gll(pK + 1024, dk + 1024); };
  auto stageVM = [&](char* dv, char* dm) {
    gll(pV, dv); gll(pV + 1024, dv + 1024); gll(pM, dm);
  };

  const int ksw = (ln & 15) << 4;
  const int msw = (ln & 15) << 4;
  const char* msb0 = (const char*)Ms[0] + ln * 256;
  const char* msb1 = (const char*)Ms[1] + ln * 256;

  auto qk = [&](const char* ksb, f32x16& t0, f32x16& t1) {
#pragma unroll
    for (int e = 0; e < 16; ++e) { t0[e] = 0.0f; t1[e] = 0.0f; }
    __builtin_amdgcn_s_setprio(1);
#pragma unroll
    for (int ks = 0; ks < 8; ++ks) {
      const int byte = (ks * 32 + hi * 16) ^ ksw;
      bf16x8 k0 = *(const bf16x8*)(ksb + (ln << 8) + byte);
      bf16x8 k1 = *(const bf16x8*)(ksb + ((32 + ln) << 8) + byte);
      t0 = __builtin_amdgcn_mfma_f32_32x32x16_bf16(k0, aq[ks], t0, 0, 0, 0);
      t1 = __builtin_amdgcn_mfma_f32_32x32x16_bf16(k1, aq[ks], t1, 0, 0, 0);
    }
    __builtin_amdgcn_s_setprio(0);
  };

  f32x16 o[4];
#pragma unroll
  for (int nt = 0; nt < 4; ++nt)
#pragma unroll
    for (int e = 0; e < 16; ++e) o[nt][e] = 0.0f;
  float lsum = 0.0f;

  // body(t): stage K(t+2)->Ks[cur], VM(t+1)->buf[nxt]; softmax(t) from sC;
  // QK(t+1)->sN from Ks[nxt]; PV(t); barrier. Pointers pre-advanced.
  auto body = [&](int t, f32x16& sC0, f32x16& sC1, f32x16& sN0, f32x16& sN1) {
    const int cur = t & 1;

    stageK(cur ? dK1 : dK0);
    stageVM(cur ? dV0 : dV1, cur ? dM0 : dM1);
    if (t + 3 < NT) pK += 16384;     // next body stages K(t+3)
    if (t + 2 < NT) { pV += 16384; pM += 256; }
    __builtin_amdgcn_sched_barrier(0);

    // ---- softmax(t): p = exp2(sC + mk*L2E)  [VALU chain first] ----
    const char* msb = cur ? msb1 : msb0;
    unsigned own0[8], own1[8];
    float psum = 0.0f;
#pragma unroll
    for (int gq = 0; gq < 4; ++gq) {
      float4 m0 = *(const float4*)(msb + ((gq * 32 + hi * 16) ^ msw));
      float4 m1 = *(const float4*)(msb + ((128 + gq * 32 + hi * 16) ^ msw));
      float p0 = __builtin_exp2f(__builtin_fmaf(m0.x, L2E, sC0[4 * gq + 0]));
      float p1 = __builtin_exp2f(__builtin_fmaf(m0.y, L2E, sC0[4 * gq + 1]));
      float p2 = __builtin_exp2f(__builtin_fmaf(m0.z, L2E, sC0[4 * gq + 2]));
      float p3 = __builtin_exp2f(__builtin_fmaf(m0.w, L2E, sC0[4 * gq + 3]));
      float q0 = __builtin_exp2f(__builtin_fmaf(m1.x, L2E, sC1[4 * gq + 0]));
      float q1 = __builtin_exp2f(__builtin_fmaf(m1.y, L2E, sC1[4 * gq + 1]));
      float q2 = __builtin_exp2f(__builtin_fmaf(m1.z, L2E, sC1[4 * gq + 2]));
      float q3 = __builtin_exp2f(__builtin_fmaf(m1.w, L2E, sC1[4 * gq + 3]));
      psum += ((p0 + p1) + (p2 + p3)) + ((q0 + q1) + (q2 + q3));
      own0[2 * gq] = pk2(p0, p1); own0[2 * gq + 1] = pk2(p2, p3);
      own1[2 * gq] = pk2(q0, q1); own1[2 * gq + 1] = pk2(q2, q3);
    }
    lsum += psum;

    // ---- QK(t+1) -> sN (independent; MFMAs fill softmax's VALU gaps) ----
    qk((const char*)Ks[cur ^ 1], sN0, sN1);

    // ---- P B-frags (permlane32_swap; verified) ----
    union Frag { unsigned u[4]; bf16x8 b; };
    Frag pf[4];
#pragma unroll
    for (int ks = 0; ks < 4; ++ks) {
      const unsigned* ow = (ks < 2) ? own0 : own1;
      const int bsl = (ks & 1) * 4;
#if __has_builtin(__builtin_amdgcn_permlane32_swap)
      u32x2 r0 = __builtin_amdgcn_permlane32_swap(ow[bsl + 0], ow[bsl + 2], false, false);
      u32x2 r1 = __builtin_amdgcn_permlane32_swap(ow[bsl + 1], ow[bsl + 3], false, false);
      pf[ks].u[0] = r0.x; pf[ks].u[2] = r0.y;
      pf[ks].u[1] = r1.x; pf[ks].u[3] = r1.y;
#else
      unsigned sA = __shfl_xor(ow[bsl + 0], 32), sCx = __shfl_xor(ow[bsl + 2], 32);
      unsigned sB = __shfl_xor(ow[bsl + 1], 32), sD = __shfl_xor(ow[bsl + 3], 32);
      pf[ks].u[0] = hi ? sCx : ow[bsl + 0];
      pf[ks].u[1] = hi ? sD : ow[bsl + 1];
      pf[ks].u[2] = hi ? ow[bsl + 2] : sA;
      pf[ks].u[3] = hi ? ow[bsl + 3] : sB;
#endif
    }

    // ---- PV(t): O^T[d][q] += V^T · P ----
    const char* vtb = (const char*)Vt[cur];
    __builtin_amdgcn_s_setprio(1);
#pragma unroll
    for (int nt = 0; nt < 4; ++nt) {
      const int d = nt * 32 + ln;
      const int swz = (((d >> 3) ^ (d >> 1)) & 3) << 4;
#pragma unroll
      for (int ks = 0; ks < 4; ++ks) {
        const int base = (ks >> 1) * 8192 + (d << 6);
        bf16x8 vfr = *(const bf16x8*)(vtb + base + (((ks & 1) * 32 + hi * 16) ^ swz));
        o[nt] = __builtin_amdgcn_mfma_f32_32x32x16_bf16(vfr, pf[ks].b, o[nt], 0, 0, 0);
      }
    }
    __builtin_amdgcn_s_setprio(0);

    __syncthreads();
  };

  // ---- prologue: K(0)->Ks[0], K(1)->Ks[1], V/M(0)->buf0; QK(0)->sA ----
  stageK(dK0); pK += 16384;         // staged K(0); pK -> K(1)
  stageK(dK1); pK += 16384;         // staged K(1); pK -> K(2)
  stageVM(dV0, dM0); pV += 16384; pM += 256;   // staged V/M(0); -> (1)
  __syncthreads();
  f32x16 sA0, sA1, sB0, sB1;
  qk((const char*)Ks[0], sA0, sA1);
  __syncthreads();   // all waves done reading Ks[0] before body(0) restages it

  for (int t = 0; t < NT; t += 2) {
    body(t, sA0, sA1, sB0, sB1);
    body(t + 1, sB0, sB1, sA0, sA1);
  }

  // ---- epilogue: O^T/l, write context[q][b][h*128+d] ----
  const float ltot = lsum + __shfl_xor(lsum, 32);
  const float invl = 1.0f / ltot;
  float* outp = Og + (size_t)(qb + ln) * (Bn * Hn * Dn) + (size_t)b * (Hn * Dn) + h * Dn;
#pragma unroll
  for (int nt = 0; nt < 4; ++nt)
#pragma unroll
    for (int gq = 0; gq < 4; ++gq) {
      float4 v;
      v.x = o[nt][gq * 4 + 0] * invl;
      v.y = o[nt][gq * 4 + 1] * invl;
      v.z = o[nt][gq * 4 + 2] * invl;
      v.w = o[nt][gq * 4 + 3] * invl;
      *(float4*)(outp + nt * 32 + gq * 8 + hi * 4) = v;
    }
}

extern "C" void kernel_launch(void* const* d_in, const int* in_sizes, int n_in,
                              void* d_out, int out_size, void* d_ws, size_t ws_size,
                              hipStream_t stream) {
  const float* q = (const float*)d_in[0];
  const float* k = (const float*)d_in[1];
  const float* v = (const float*)d_in[2];
  const float* m = (const float*)d_in[3];
  float* out = (float*)d_out;
  char* wsK = (char*)d_ws;
  char* wsV = wsK + WSK_BYTES;

  prepack<<<dim3((Bn * Gn * KVn * 64) / 256), 256, 0, stream>>>(k, v, wsK, wsV);
  dim3 grid(Qn / QBLK, Hn / HO, Bn);
  attn_fwd<<<grid, WAVES * 64, 0, stream>>>(q, m, wsK, wsV, out);
}